// Round 1
// baseline (77.652 us; speedup 1.0000x reference)
//
#include <hip/hip_runtime.h>

#define NBLK 256
#define NTHR 256

// Compute raw values + edge-corrected 9x9 box-mean high-pass (dist) for one pixel.
__device__ __forceinline__ void compute_dists(const float* __restrict__ pred,
                                              const float* __restrict__ tgt,
                                              int idx, float& pv, float& tv,
                                              float& pd, float& td) {
    int b   = idx >> 14;          // image index (4 images of 128*128)
    int rem = idx & 16383;
    int i   = rem >> 7;
    int j   = rem & 127;
    const float* p = pred + (b << 14);
    const float* t = tgt  + (b << 14);
    float sp = 0.f, st = 0.f;
#pragma unroll
    for (int di = -4; di <= 4; ++di) {
        int ii = i + di;
        if ((unsigned)ii >= 128u) continue;
        int base = ii << 7;
#pragma unroll
        for (int dj = -4; dj <= 4; ++dj) {
            int jj = j + dj;
            if ((unsigned)jj >= 128u) continue;
            sp += p[base + jj];
            st += t[base + jj];
        }
    }
    int rc = min(i, 4) + min(127 - i, 4) + 1;   // valid rows in window
    int cc = min(j, 4) + min(127 - j, 4) + 1;   // valid cols in window
    float den = (float)(rc * cc);
    pv = p[(i << 7) + j];
    tv = t[(i << 7) + j];
    pd = pv - sp / den;
    td = tv - st / den;
}

// k1: per-pixel wmse term + min/max of dists; block-reduce to partials.
__global__ void SPL_k1(const float* __restrict__ pred, const float* __restrict__ tgt,
                       float* __restrict__ part) {
    int idx = blockIdx.x * NTHR + threadIdx.x;
    float pv, tv, pd, td;
    compute_dists(pred, tgt, idx, pv, tv, pd, td);

    // threshold-weighted MSE weight: last satisfied threshold wins
    float w = 1.f;
    if (tv >= 0.5f) w = 2.f;
    if (tv >= 2.f)  w = 5.f;
    if (tv >= 5.f)  w = 10.f;
    if (tv >= 10.f) w = 30.f;
    float d  = pv - tv;
    float s  = w * d * d;
    float mn = fminf(pd, td);
    float mx = fmaxf(pd, td);

    for (int o = 32; o > 0; o >>= 1) {
        s  += __shfl_down(s, o, 64);
        mn  = fminf(mn, __shfl_down(mn, o, 64));
        mx  = fmaxf(mx, __shfl_down(mx, o, 64));
    }
    __shared__ float ss[4], smn[4], smx[4];
    int lane = threadIdx.x & 63, wid = threadIdx.x >> 6;
    if (lane == 0) { ss[wid] = s; smn[wid] = mn; smx[wid] = mx; }
    __syncthreads();
    if (threadIdx.x == 0) {
        part[blockIdx.x]            = ss[0] + ss[1] + ss[2] + ss[3];
        part[NBLK + blockIdx.x]     = fminf(fminf(smn[0], smn[1]), fminf(smn[2], smn[3]));
        part[2 * NBLK + blockIdx.x] = fmaxf(fmaxf(smx[0], smx[1]), fmaxf(smx[2], smx[3]));
    }
}

// k2: reduce 256 partials -> scal[0]=lo, scal[1]=hi, scal[2]=sum(wmse)
__global__ void SPL_k2(const float* __restrict__ part, float* __restrict__ scal) {
    int tid = threadIdx.x;
    float s  = part[tid];
    float mn = part[NBLK + tid];
    float mx = part[2 * NBLK + tid];
    for (int o = 32; o > 0; o >>= 1) {
        s  += __shfl_down(s, o, 64);
        mn  = fminf(mn, __shfl_down(mn, o, 64));
        mx  = fmaxf(mx, __shfl_down(mx, o, 64));
    }
    __shared__ float ss[4], smn[4], smx[4];
    int lane = tid & 63, wid = tid >> 6;
    if (lane == 0) { ss[wid] = s; smn[wid] = mn; smx[wid] = mx; }
    __syncthreads();
    if (tid == 0) {
        scal[0] = fminf(fminf(smn[0], smn[1]), fminf(smn[2], smn[3]));  // lo
        scal[1] = fmaxf(fmaxf(smx[0], smx[1]), fmaxf(smx[2], smx[3]));  // hi
        scal[2] = ss[0] + ss[1] + ss[2] + ss[3];                        // wmse sum
    }
}

// k3: analytic grid-point count per pixel: #{k in [0,999] : x_k in [a, b)},
// x_k = lo + k*dx, dx = (hi-lo)/999. count = ceil((b-lo)/dx) - ceil((a-lo)/dx).
__global__ void SPL_k3(const float* __restrict__ pred, const float* __restrict__ tgt,
                       const float* __restrict__ scal, int* __restrict__ cpart) {
    int idx = blockIdx.x * NTHR + threadIdx.x;
    float pv, tv, pd, td;
    compute_dists(pred, tgt, idx, pv, tv, pd, td);

    float lo = scal[0], hi = scal[1];
    float dx = (hi - lo) / 999.0f;
    float a  = fminf(pd, td);
    float b  = fmaxf(pd, td);
    int ka = (int)ceilf((a - lo) / dx);
    int kb = (int)ceilf((b - lo) / dx);
    if (ka < 0) ka = 0;
    if (kb > 1000) kb = 1000;
    int cnt = kb - ka;
    if (cnt < 0) cnt = 0;

    for (int o = 32; o > 0; o >>= 1) cnt += __shfl_down(cnt, o, 64);
    __shared__ int sc[4];
    int lane = threadIdx.x & 63, wid = threadIdx.x >> 6;
    if (lane == 0) sc[wid] = cnt;
    __syncthreads();
    if (threadIdx.x == 0) cpart[blockIdx.x] = sc[0] + sc[1] + sc[2] + sc[3];
}

// k4: reduce count partials, combine into final scalar loss.
__global__ void SPL_k4(const int* __restrict__ cpart, const float* __restrict__ scal,
                       float* __restrict__ out) {
    int tid = threadIdx.x;
    int c = cpart[tid];
    for (int o = 32; o > 0; o >>= 1) c += __shfl_down(c, o, 64);
    __shared__ int sc[4];
    int lane = tid & 63, wid = tid >> 6;
    if (lane == 0) sc[wid] = c;
    __syncthreads();
    if (tid == 0) {
        long long total = (long long)sc[0] + sc[1] + sc[2] + sc[3];
        float lo = scal[0], hi = scal[1];
        float dx = (hi - lo) / 999.0f;
        float wmse = scal[2] * (1.0f / 65536.0f);
        double crps = (double)total * (double)dx / 65536.0;
        out[0] = 1e-4f * wmse + (float)crps;
    }
}

extern "C" void kernel_launch(void* const* d_in, const int* in_sizes, int n_in,
                              void* d_out, int out_size, void* d_ws, size_t ws_size,
                              hipStream_t stream) {
    const float* pred = (const float*)d_in[0];
    const float* tgt  = (const float*)d_in[1];
    float* part  = (float*)d_ws;          // 3*256 floats
    float* scal  = part + 3 * NBLK;       // 3 floats (pad to 4)
    int*   cpart = (int*)(scal + 4);      // 256 ints
    float* out   = (float*)d_out;

    SPL_k1<<<NBLK, NTHR, 0, stream>>>(pred, tgt, part);
    SPL_k2<<<1, NBLK, 0, stream>>>(part, scal);
    SPL_k3<<<NBLK, NTHR, 0, stream>>>(pred, tgt, scal, cpart);
    SPL_k4<<<1, NBLK, 0, stream>>>(cpart, scal, out);
}

// Round 2
// 76.975 us; speedup vs baseline: 1.0088x; 1.0088x over previous
//
#include <hip/hip_runtime.h>

// ws layout: part_s[256] | part_mn[256] | part_mx[256] | float2 dist[65536]

__global__ __launch_bounds__(256) void SPL_kA(const float* __restrict__ pred,
                                              const float* __restrict__ tgt,
                                              float* __restrict__ part,
                                              float2* __restrict__ dist) {
    __shared__ float sP[1280], sT[1280];   // 10 rows x 128 cols, zero-padded
    __shared__ float vsP[256], vsT[256];   // vertical 9-sums for the 2 output rows
    __shared__ float red[12];

    int b = blockIdx.x;
    int t = threadIdx.x;
    int m  = b >> 6;              // image 0..3
    int r2 = (b & 63) << 1;       // first of the 2 output rows
    const float* p = pred + (m << 14);
    const float* q = tgt  + (m << 14);

    // stage rows r2-4 .. r2+5 (zero-pad out-of-image)
#pragma unroll
    for (int s = 0; s < 5; ++s) {
        int k   = t + s * 256;    // 0..1279
        int rr  = k >> 7;         // 0..9
        int cc  = k & 127;
        int grw = r2 - 4 + rr;
        bool ok = (unsigned)grw < 128u;
        sP[k] = ok ? p[(grw << 7) + cc] : 0.f;
        sT[k] = ok ? q[(grw << 7) + cc] : 0.f;
    }
    __syncthreads();

    int orow = t >> 7;            // 0/1
    int col  = t & 127;
    int row  = r2 + orow;

    // vertical 9-sum at this column (LDS rows orow .. orow+8)
    float vp = 0.f, vt = 0.f;
    int vb = orow * 128 + col;
#pragma unroll
    for (int di = 0; di < 9; ++di) {
        vp += sP[vb + di * 128];
        vt += sT[vb + di * 128];
    }
    vsP[t] = vp; vsT[t] = vt;
    __syncthreads();

    // horizontal 9-sum with column bounds
    float sp = 0.f, st = 0.f;
    int rbase = t & ~127;
#pragma unroll
    for (int dj = -4; dj <= 4; ++dj) {
        int jj = col + dj;
        if ((unsigned)jj < 128u) { sp += vsP[rbase + jj]; st += vsT[rbase + jj]; }
    }

    int   rc  = min(row, 4) + min(127 - row, 4) + 1;
    int   cn  = min(col, 4) + min(127 - col, 4) + 1;
    float den = (float)(rc * cn);
    float pv  = sP[(orow + 4) * 128 + col];
    float tv  = sT[(orow + 4) * 128 + col];
    float pd  = pv - sp / den;
    float td  = tv - st / den;

    dist[(b << 8) + t] = make_float2(pd, td);

    // threshold-weighted MSE term
    float w = 1.f;
    if (tv >= 0.5f) w = 2.f;
    if (tv >= 2.f)  w = 5.f;
    if (tv >= 5.f)  w = 10.f;
    if (tv >= 10.f) w = 30.f;
    float d  = pv - tv;
    float s  = w * d * d;
    float mn = fminf(pd, td);
    float mx = fmaxf(pd, td);

    for (int o = 32; o > 0; o >>= 1) {
        s  += __shfl_down(s, o, 64);
        mn  = fminf(mn, __shfl_down(mn, o, 64));
        mx  = fmaxf(mx, __shfl_down(mx, o, 64));
    }
    int lane = t & 63, wid = t >> 6;
    if (lane == 0) { red[wid] = s; red[4 + wid] = mn; red[8 + wid] = mx; }
    __syncthreads();
    if (t == 0) {
        part[b]       = red[0] + red[1] + red[2] + red[3];
        part[256 + b] = fminf(fminf(red[4], red[5]), fminf(red[6], red[7]));
        part[512 + b] = fmaxf(fmaxf(red[8], red[9]), fmaxf(red[10], red[11]));
    }
}

// 1 block x 1024 threads: reduce partials -> lo/hi/wmse, analytic CRPS count, final loss
__global__ __launch_bounds__(1024) void SPL_kB(const float* __restrict__ part,
                                               const float2* __restrict__ dist,
                                               float* __restrict__ out) {
    __shared__ float rs[16], rmn[16], rmx[16];
    __shared__ int   rci[16];
    __shared__ float bc[3];   // lo, hi, wmse-sum

    int t = threadIdx.x;
    int lane = t & 63, wid = t >> 6;   // 16 waves

    float s = 0.f, mn = 3.4e38f, mx = -3.4e38f;
    if (t < 256) { s = part[t]; mn = part[256 + t]; mx = part[512 + t]; }
    for (int o = 32; o > 0; o >>= 1) {
        s  += __shfl_down(s, o, 64);
        mn  = fminf(mn, __shfl_down(mn, o, 64));
        mx  = fmaxf(mx, __shfl_down(mx, o, 64));
    }
    if (lane == 0) { rs[wid] = s; rmn[wid] = mn; rmx[wid] = mx; }
    __syncthreads();
    if (t == 0) {
        float ss = 0.f, m1 = 3.4e38f, m2 = -3.4e38f;
        for (int i = 0; i < 16; ++i) {
            ss += rs[i]; m1 = fminf(m1, rmn[i]); m2 = fmaxf(m2, rmx[i]);
        }
        bc[0] = m1; bc[1] = m2; bc[2] = ss;
    }
    __syncthreads();

    float lo = bc[0], hi = bc[1];
    float dx = (hi - lo) / 999.0f;

    // count grid points x_k = lo + k*dx, k in [0,1000), falling in [a, b)
    int cnt = 0;
#pragma unroll 4
    for (int it = 0; it < 64; ++it) {
        float2 d = dist[it * 1024 + t];
        float a  = fminf(d.x, d.y);
        float b2 = fmaxf(d.x, d.y);
        int ka = (int)ceilf((a - lo) / dx);
        int kb = (int)ceilf((b2 - lo) / dx);
        if (ka < 0) ka = 0;
        if (kb > 1000) kb = 1000;
        int c = kb - ka;
        if (c > 0) cnt += c;
    }
    for (int o = 32; o > 0; o >>= 1) cnt += __shfl_down(cnt, o, 64);
    if (lane == 0) rci[wid] = cnt;
    __syncthreads();
    if (t == 0) {
        long long tot = 0;
        for (int i = 0; i < 16; ++i) tot += rci[i];
        float  wmse = bc[2] * (1.0f / 65536.0f);
        double crps = (double)tot * (double)dx / 65536.0;
        out[0] = 1e-4f * wmse + (float)crps;
    }
}

extern "C" void kernel_launch(void* const* d_in, const int* in_sizes, int n_in,
                              void* d_out, int out_size, void* d_ws, size_t ws_size,
                              hipStream_t stream) {
    const float* pred = (const float*)d_in[0];
    const float* tgt  = (const float*)d_in[1];
    float*  part = (float*)d_ws;                 // 768 floats
    float2* dist = (float2*)(part + 768);        // 65536 float2 = 512 KB
    float*  out  = (float*)d_out;

    SPL_kA<<<256, 256, 0, stream>>>(pred, tgt, part, dist);
    SPL_kB<<<1, 1024, 0, stream>>>(part, dist, out);
}